// Round 15
// baseline (1106.683 us; speedup 1.0000x reference)
//
#include <hip/hip_runtime.h>
#include <hip/hip_fp16.h>
#include <math.h>

#define TWO_PI_F  6.2831853071795864769f
#define INV_2PI_F 0.15915494309189533577f

constexpr int T     = 256;
constexpr int BATCH = 32;
constexpr int NIN   = 28;
constexpr int NH    = 1024;
constexpr int NOUT  = 10;

constexpr int NBLK = 64;     // 16 row-groups x 4 batch-groups
constexpr int NTHR = 512;    // 8 waves: wave w = K-slice (K=128 each)

typedef unsigned int   uint;
typedef unsigned short ushort;
typedef unsigned long long ull;
typedef _Float16 half8 __attribute__((ext_vector_type(8)));
typedef float    f32x4 __attribute__((ext_vector_type(4)));

// ---- ws byte offsets ----
constexpr size_t OFF_W16 = 0;                                    // ushort [1024][1024] fp16 W = 2 MB
constexpr size_t OFF_INP = 2ull * 1024 * 1024;                   // float [T][BATCH][NH] (REVOLUTIONS) = 32 MB
constexpr size_t OFF_SCT = OFF_INP + (size_t)T * NH * BATCH * 4; // ushort [2][4][16][1024] = 256 KB
constexpr size_t OFF_STF = OFF_SCT + 2ull * 4 * 16 * 1024 * 2;   // float [BATCH][NH] = 128 KB
constexpr size_t OFF_FLG = OFF_STF + (size_t)BATCH * NH * 4;     // per-WAVE flags: 4*16*8 x 128B = 64 KB

// pd row stride (16 distinct banks for m=0..15)
constexpr int PDS = 21;

// keep a value live: forces the returning atomic whose vmcnt ACK = executed-at-LLC.
__device__ __forceinline__ void sink(uint v) { asm volatile("" :: "v"(v)); }
__device__ __forceinline__ void sink64(ull v) { asm volatile("" :: "v"(v)); }

// LLC-point publish, ACK-drained (data words -- drain required before flag).
__device__ __forceinline__ void stx(uint* p, uint v)   { sink(atomicExch(p, v)); }
__device__ __forceinline__ void stx64(ull* p, ull v)   { sink64(atomicExch(p, v)); }

// LDS-only barrier: orders pd stores/reads across waves WITHOUT draining vmcnt
// (outstanding publishes + inp prefetch stay in flight).
#define BAR_LDS() asm volatile("s_waitcnt lgkmcnt(0)\n\ts_barrier" ::: "memory")

// B-fragment load: 4 x dwordx4 at 64B stride, one waitcnt (sc1 -> LLC).
__device__ __forceinline__ void ldB4(const ushort* base, uint4 bf[4]) {
  asm volatile(
    "global_load_dwordx4 %0, %4, off sc1\n\t"
    "global_load_dwordx4 %1, %4, off offset:64 sc1\n\t"
    "global_load_dwordx4 %2, %4, off offset:128 sc1\n\t"
    "global_load_dwordx4 %3, %4, off offset:192 sc1\n\t"
    "s_waitcnt vmcnt(0)"
    : "=&v"(bf[0]), "=&v"(bf[1]), "=&v"(bf[2]), "=&v"(bf[3])
    : "v"(base)
    : "memory");
}

// Per-wave dependency wait: wave w's K-slice is produced by blocks 2w,2w+1;
// with per-WAVE flags it needs all 8 wave-flags of each (16 flags, lanes 0-15).
// Bounded: protocol error -> fast miscompare, not a harness hang.
__device__ __forceinline__ void wave_wait16(unsigned* flags, unsigned step,
                                            int lane, int bg, int w, bool* broken) {
  if (*broken) return;
  if (lane < 16) {
    const unsigned* fp =
        &flags[(((bg * 16) + 2 * w + (lane >> 3)) * 8 + (lane & 7)) * 32];
    int g = 0;
    while (__hip_atomic_load(fp, __ATOMIC_RELAXED, __HIP_MEMORY_SCOPE_AGENT) < step)
      if (++g > 300000) { *broken = true; break; }
  }
}

// ---- prep: W -> fp16 ----
__global__ __launch_bounds__(256) void prep_w16(const float* __restrict__ Wh,
                                                ushort* __restrict__ w16) {
  const int m = blockIdx.x * 256 + threadIdx.x;
  w16[m] = __builtin_bit_cast(ushort, (_Float16)Wh[m]);
}

// ---- prep: inp_rev[t][b][i] = (Wi_w[i,:]·x[t,b,:] + Wi_b[i] + omega[i]) / 2pi ----
__global__ __launch_bounds__(256) void prep_inp(const float* __restrict__ x,
                                                const float* __restrict__ Wi_w,
                                                const float* __restrict__ Wi_b,
                                                const float* __restrict__ omega,
                                                float* __restrict__ inp) {
  const int t = blockIdx.x;
  const int b = blockIdx.y;
  const float* xr = x + ((size_t)t * BATCH + b) * NIN;
#pragma unroll
  for (int u = 0; u < 4; ++u) {
    const int i = u * 256 + threadIdx.x;
    const float* wr = Wi_w + (size_t)i * NIN;
    float acc = Wi_b[i] + omega[i];
#pragma unroll
    for (int k = 0; k < NIN; ++k) acc += xr[k] * wr[k];
    inp[((size_t)t * BATCH + b) * NH + i] = acc * INV_2PI_F;
  }
}

// ---- the scan: per-WAVE flags, ONE LDS barrier/step, hw trig in revolutions.
// Anti-overwrite safety (two-step lag, re-proven for per-wave flags): block Z's
// wave-flag t implies Z passed BAR_LDS(t) implies ALL Z waves finished their
// buffer-p reads at step t. Block Y rewrites buffer p at end of step t+1, which
// it reaches only after its waves collectively observed ALL 16 blocks' wave
// flags >= t+2 -- published after those blocks' BAR_LDS, i.e. after their
// buffer-p reads. Single-LLC-timeline ordering, as in all proven rounds.
__global__ __launch_bounds__(NTHR) void kuramoto_scan(
    const float*  __restrict__ inp,   // [T][BATCH][NH], revolutions
    const ushort* __restrict__ w16,   // [1024][1024] fp16
    ushort*       __restrict__ scT,   // [2][4 bg][16 n][1024 i]; n: 0-7 sin, 8-15 cos
    float*        __restrict__ stF,   // [BATCH][NH], revolutions (scaled at write)
    unsigned*     __restrict__ flags) // per-wave: [(bg*16+rg)*8 + wave]*32
{
  // D-partials, DOUBLE-buffered: pd[parity][w][rt][n][row16 pad] -> no 2nd barrier
  __shared__ float pd[2][8 * 4 * 16 * PDS];   // 84 KB (1 block/CU; grid is 64 on 256 CUs)

  const int tid  = threadIdx.x;
  const int bid  = blockIdx.x;
  const int rg   = bid >> 2;       // row-group: rows rg*64 .. +63
  const int bg   = bid & 3;        // batch-group: batches bg*8 .. +7
  const int lane = tid & 63;
  const int w    = tid >> 6;       // K-slice 0..7 == wave id
  const int m    = lane & 15;      // A: M index / B,D: N index
  const int quad = lane >> 4;

  // ---- A-fragments: rows {rt*16+m} x K-slice w, 16 frags x 4 VGPR ----
  half8 af[16];
  {
    const ushort* wbase = w16 + (size_t)(rg * 64 + m) * NH + w * 128 + quad * 8;
#pragma unroll
    for (int rt = 0; rt < 4; ++rt)
#pragma unroll
      for (int j = 0; j < 4; ++j)
        af[rt * 4 + j] = __builtin_bit_cast(half8,
            *(const uint4*)(wbase + (size_t)rt * 16 * NH + j * 32));
  }

  // ---- theta-phase identity: wave bl = batch, lane ilc = hidden unit ----
  const int bl = tid >> 6;         // 0..7 (== w)
  const int ilc = tid & 63;        // 0..63
  const int i  = rg * 64 + ilc;    // my hidden unit
  const int b  = bg * 8 + bl;      // my batch
  float th = 0.f, s_own = 0.f, c_own = 1.f;   // th in REVOLUTIONS
  bool broken = false;

  // ---- init parity-0 state (32-bit far atomics, sink-drained), per-wave flag=1 ----
  {
    if ((ilc & 1) == 0)
      stx((uint*)(scT + ((size_t)(0 * 4 + bg) * 16 + bl) * 1024 + i), 0x00000000u);       // sin = 0,0
    else
      stx((uint*)(scT + ((size_t)(0 * 4 + bg) * 16 + bl + 8) * 1024 + (i - 1)), 0x3C003C00u); // cos = 1,1
    if (lane == 0)
      atomicExch(&flags[(((size_t)bg * 16 + rg) * 8 + w) * 32], 1u);   // no-return: no ACK wait
  }

  float inpv = inp[(size_t)b * NH + i];   // t=0 prefetch drains under the wait

  for (int t = 0; t < T; ++t) {
    const int p = t & 1;
    const uint stepv = (uint)(t + 1);

    // ---- per-wave wait on my 16 producer wave-flags, then load my B-slice ----
    wave_wait16(flags, stepv, lane, bg, w, &broken);
    uint4 bf[4];
    ldB4(scT + ((size_t)(p * 4 + bg) * 16 + m) * 1024 + w * 128 + quad * 8, bf);

    // ---- MFMA: 4 independent chains of 4 (one per row-tile) ----
    f32x4 D0 = {0.f, 0.f, 0.f, 0.f}, D1 = {0.f, 0.f, 0.f, 0.f};
    f32x4 D2 = {0.f, 0.f, 0.f, 0.f}, D3 = {0.f, 0.f, 0.f, 0.f};
#pragma unroll
    for (int j = 0; j < 4; ++j) {
      const half8 bh = __builtin_bit_cast(half8, bf[j]);
      D0 = __builtin_amdgcn_mfma_f32_16x16x32_f16(af[0 * 4 + j], bh, D0, 0, 0, 0);
      D1 = __builtin_amdgcn_mfma_f32_16x16x32_f16(af[1 * 4 + j], bh, D1, 0, 0, 0);
      D2 = __builtin_amdgcn_mfma_f32_16x16x32_f16(af[2 * 4 + j], bh, D2, 0, 0, 0);
      D3 = __builtin_amdgcn_mfma_f32_16x16x32_f16(af[3 * 4 + j], bh, D3, 0, 0, 0);
    }

    // pd[parity][w][rt][m][quad*4..]
    float* pdp = pd[p];
    *(f32x4*)&pdp[(((w * 4 + 0) * 16) + m) * PDS + quad * 4] = D0;
    *(f32x4*)&pdp[(((w * 4 + 1) * 16) + m) * PDS + quad * 4] = D1;
    *(f32x4*)&pdp[(((w * 4 + 2) * 16) + m) * PDS + quad * 4] = D2;
    *(f32x4*)&pdp[(((w * 4 + 3) * 16) + m) * PDS + quad * 4] = D3;
    BAR_LDS();   // THE one barrier: all waves' pd[p] ready (lgkm only, no vmcnt drain)

    // ---- theta update (revolutions, hw trig) ----
    const int rti = ilc >> 4, r16 = ilc & 15;
    float S = 0.f, C = 0.f;
#pragma unroll
    for (int ww = 0; ww < 8; ++ww) {
      S += pdp[((ww * 4 + rti) * 16 + bl) * PDS + r16];
      C += pdp[((ww * 4 + rti) * 16 + bl + 8) * PDS + r16];
    }
    const float coup = s_own * C - c_own * S;   // sin*ΣWcos - cos*ΣWsin (radians)
    const float thn = th + coup * INV_2PI_F + inpv;
    asm("v_fract_f32 %0, %1" : "=v"(th) : "v"(thn));       // exact mod-1, [0,1)
    asm("v_sin_f32 %0, %1" : "=v"(s_own) : "v"(th));       // sin(th*2pi)
    asm("v_cos_f32 %0, %1" : "=v"(c_own) : "v"(th));       // cos(th*2pi)

    if (t == T - 1) break;

    // ---- per-wave publish (packed 64-bit far atomics, sink-drained) + own flag.
    // No block barrier: early waves' flags fly as soon as THEIR data is ACKed.
    const uint hs = __builtin_bit_cast(ushort, (_Float16)s_own);
    const uint hc = __builtin_bit_cast(ushort, (_Float16)c_own);
    const uint phs = (uint)__shfl_xor((int)hs, 1, 64);
    const uint phc = (uint)__shfl_xor((int)hc, 1, 64);
    const uint pw = hs | (phs << 16);
    const uint cw = phc | (hc << 16);
    const uint pw2 = (uint)__shfl_xor((int)pw, 2, 64);
    const uint cw2 = (uint)__shfl_xor((int)cw, 2, 64);
    const size_t dbase = (size_t)((p ^ 1) * 4 + bg) * 16;
    if ((ilc & 3) == 0)
      stx64((ull*)(scT + (dbase + bl) * 1024 + i), (ull)pw | ((ull)pw2 << 32));
    else if ((ilc & 3) == 1)
      stx64((ull*)(scT + (dbase + bl + 8) * 1024 + (i - 1)), (ull)cw | ((ull)cw2 << 32));
    // wave-wide vmcnt drained by the sinks above => data at LLC before flag
    if (lane == 0)
      atomicExch(&flags[(((size_t)bg * 16 + rg) * 8 + w) * 32], stepv + 1u);

    inpv = inp[((size_t)(t + 1) * BATCH + b) * NH + i];   // drains under next wait
  }

  stF[(size_t)b * NH + i] = th * TWO_PI_F;   // revolutions -> radians
}

// ---- readout ----
__global__ void readout(const float* __restrict__ stF,
                        const float* __restrict__ Wout,   // [10][1024]
                        const float* __restrict__ bout,   // [10]
                        float* __restrict__ out)          // [32][10]
{
  const int bb = blockIdx.x;
  const int lane = threadIdx.x;   // 64 threads
  float st[16];
#pragma unroll
  for (int u = 0; u < 16; ++u) st[u] = stF[(size_t)bb * NH + u * 64 + lane];
  for (int o = 0; o < NOUT; ++o) {
    float acc = 0.f;
#pragma unroll
    for (int u = 0; u < 16; ++u) acc += st[u] * Wout[o * NH + u * 64 + lane];
#pragma unroll
    for (int sh = 1; sh < 64; sh <<= 1) acc += __shfl_xor(acc, sh, 64);
    if (lane == 0) out[bb * NOUT + o] = acc + bout[o];
  }
}

extern "C" void kernel_launch(void* const* d_in, const int* in_sizes, int n_in,
                              void* d_out, int out_size, void* d_ws, size_t ws_size,
                              hipStream_t stream) {
  const float* x     = (const float*)d_in[0];
  const float* Wi_w  = (const float*)d_in[1];
  const float* Wi_b  = (const float*)d_in[2];
  const float* Wh    = (const float*)d_in[3];
  const float* omega = (const float*)d_in[4];
  const float* W_out = (const float*)d_in[5];
  const float* b_out = (const float*)d_in[6];

  char* ws = (char*)d_ws;
  ushort*   w16 = (ushort*)(ws + OFF_W16);
  float*    inp = (float*)(ws + OFF_INP);
  ushort*   scT = (ushort*)(ws + OFF_SCT);
  float*    stF = (float*)(ws + OFF_STF);
  unsigned* flg = (unsigned*)(ws + OFF_FLG);

  (void)hipMemsetAsync(ws + OFF_FLG, 0, 65536, stream);   // 512 per-wave flags x 128B

  prep_w16<<<dim3(NH * NH / 256), dim3(256), 0, stream>>>(Wh, w16);
  prep_inp<<<dim3(T, BATCH), dim3(256), 0, stream>>>(x, Wi_w, Wi_b, omega, inp);

  void* args[] = { (void*)&inp, (void*)&w16, (void*)&scT, (void*)&stF, (void*)&flg };
  hipError_t err = hipLaunchCooperativeKernel((const void*)kuramoto_scan,
                                              dim3(NBLK), dim3(NTHR), args, 0, stream);
  if (err != hipSuccess) {
    // 64 blocks at 1 block/CU are trivially co-resident; normal launch is safe.
    (void)hipGetLastError();
    kuramoto_scan<<<dim3(NBLK), dim3(NTHR), 0, stream>>>(inp, w16, scT, stF, flg);
  }

  readout<<<dim3(BATCH), dim3(64), 0, stream>>>(stF, W_out, b_out, (float*)d_out);
}

// Round 16
// 974.275 us; speedup vs baseline: 1.1359x; 1.1359x over previous
//
#include <hip/hip_runtime.h>
#include <hip/hip_fp16.h>
#include <math.h>

#define TWO_PI_F  6.2831853071795864769f
#define INV_2PI_F 0.15915494309189533577f

constexpr int T     = 256;
constexpr int BATCH = 32;
constexpr int NIN   = 28;
constexpr int NH    = 1024;
constexpr int NOUT  = 10;

constexpr int NBLK = 64;     // 16 row-groups x 4 batch-groups
constexpr int NTHR = 512;    // 8 waves: wave w = K-slice (K=128 each)

typedef unsigned int   uint;
typedef unsigned short ushort;
typedef unsigned long long ull;
typedef _Float16 half8 __attribute__((ext_vector_type(8)));
typedef float    f32x4 __attribute__((ext_vector_type(4)));

// ---- ws byte offsets ----
constexpr size_t OFF_W16 = 0;                                    // ushort [1024][1024] fp16 W = 2 MB
constexpr size_t OFF_INP = 2ull * 1024 * 1024;                   // float [T][BATCH][NH] (REVOLUTIONS) = 32 MB
constexpr size_t OFF_SCT = OFF_INP + (size_t)T * NH * BATCH * 4; // ushort [2][4][16][1024] = 256 KB
constexpr size_t OFF_STF = OFF_SCT + 2ull * 4 * 16 * 1024 * 2;   // float [BATCH][NH] = 128 KB
constexpr size_t OFF_FLG = OFF_STF + (size_t)BATCH * NH * 4;     // step flags, 8 KB

// pd row stride: 21 floats -> 16 distinct banks for m=0..15 (r15: conflicts = 0)
constexpr int PDS = 21;

// keep a value live: forces the returning atomic whose vmcnt ACK = executed-at-LLC.
__device__ __forceinline__ void sink(uint v) { asm volatile("" :: "v"(v)); }
__device__ __forceinline__ void sink64(ull v) { asm volatile("" :: "v"(v)); }

// LLC-point publish (R9/R12-proven protocol).
__device__ __forceinline__ void stx(uint* p, uint v)   { sink(atomicExch(p, v)); }
__device__ __forceinline__ void stx64(ull* p, ull v)   { sink64(atomicExch(p, v)); }

// B-fragment load: 4 x dwordx4 at 64B stride, one waitcnt (sc1 -> LLC).
__device__ __forceinline__ void ldB4(const ushort* base, uint4 bf[4]) {
  asm volatile(
    "global_load_dwordx4 %0, %4, off sc1\n\t"
    "global_load_dwordx4 %1, %4, off offset:64 sc1\n\t"
    "global_load_dwordx4 %2, %4, off offset:128 sc1\n\t"
    "global_load_dwordx4 %3, %4, off offset:192 sc1\n\t"
    "s_waitcnt vmcnt(0)"
    : "=&v"(bf[0]), "=&v"(bf[1]), "=&v"(bf[2]), "=&v"(bf[3])
    : "v"(base)
    : "memory");
}

// Per-WAVE dependency wait: wave w's K-slice is produced by blocks 2w, 2w+1.
// (R15 lesson: per-wave flags with fan-in 16 regressed; fan-in 2 is optimal.)
__device__ __forceinline__ void wave_wait2(unsigned* flags, unsigned step,
                                           int lane, int bg, int w) {
  if (lane < 2) {
    const unsigned* fp = &flags[(bg * 16 + 2 * w + lane) * 32];
    while (__hip_atomic_load(fp, __ATOMIC_RELAXED, __HIP_MEMORY_SCOPE_AGENT) < step)
      ;   // poll period = load latency
  }
}

// Producer flag publish (R9-proven): data atomics ACKed at LLC (vmcnt drained
// by __syncthreads), then tid0 far-atomic flag.
__device__ __forceinline__ void gbar_pub(unsigned* flags, unsigned val, int tid,
                                         int rg, int bg) {
  __syncthreads();
  if (tid == 0)
    sink(atomicExch(&flags[(bg * 16 + rg) * 32], val));
}

// ---- prep: W -> fp16 ----
__global__ __launch_bounds__(256) void prep_w16(const float* __restrict__ Wh,
                                                ushort* __restrict__ w16) {
  const int m = blockIdx.x * 256 + threadIdx.x;
  w16[m] = __builtin_bit_cast(ushort, (_Float16)Wh[m]);
}

// ---- prep: inp_rev[t][b][i] = (Wi_w[i,:]·x[t,b,:] + Wi_b[i] + omega[i]) / 2pi ----
__global__ __launch_bounds__(256) void prep_inp(const float* __restrict__ x,
                                                const float* __restrict__ Wi_w,
                                                const float* __restrict__ Wi_b,
                                                const float* __restrict__ omega,
                                                float* __restrict__ inp) {
  const int t = blockIdx.x;
  const int b = blockIdx.y;
  const float* xr = x + ((size_t)t * BATCH + b) * NIN;
#pragma unroll
  for (int u = 0; u < 4; ++u) {
    const int i = u * 256 + threadIdx.x;
    const float* wr = Wi_w + (size_t)i * NIN;
    float acc = Wi_b[i] + omega[i];
#pragma unroll
    for (int k = 0; k < NIN; ++k) acc += xr[k] * wr[k];
    inp[((size_t)t * BATCH + b) * NH + i] = acc * INV_2PI_F;
  }
}

// ---- the scan: R14 structure (per-block flags, fan-in-2 wait) + hw trig in
// revolutions (R15's clean win). Lockstep/anti-overwrite: two-step-lag proof
// as in R12/R14.
__global__ __launch_bounds__(NTHR, 2) void kuramoto_scan(
    const float*  __restrict__ inp,   // [T][BATCH][NH], revolutions
    const ushort* __restrict__ w16,   // [1024][1024] fp16
    ushort*       __restrict__ scT,   // [2][4 bg][16 n][1024 i]; n: 0-7 sin, 8-15 cos
    float*        __restrict__ stF,   // [BATCH][NH], radians (scaled at write)
    unsigned*     __restrict__ flags)
{
  // D-partials: pd[w (K-slice)][rt][n][row16 (+5 pad)]
  __shared__ float pd[8 * 4 * 16 * PDS];   // 42 KB

  const int tid  = threadIdx.x;
  const int bid  = blockIdx.x;
  const int rg   = bid >> 2;       // row-group: rows rg*64 .. +63
  const int bg   = bid & 3;        // batch-group: batches bg*8 .. +7
  const int lane = tid & 63;
  const int w    = tid >> 6;       // K-slice 0..7
  const int m    = lane & 15;      // A: M index / B,D: N index
  const int quad = lane >> 4;

  // ---- A-fragments: rows {rt*16+m} x K-slice w, 16 frags x 4 VGPR ----
  half8 af[16];
  {
    const ushort* wbase = w16 + (size_t)(rg * 64 + m) * NH + w * 128 + quad * 8;
#pragma unroll
    for (int rt = 0; rt < 4; ++rt)
#pragma unroll
      for (int j = 0; j < 4; ++j)
        af[rt * 4 + j] = __builtin_bit_cast(half8,
            *(const uint4*)(wbase + (size_t)rt * 16 * NH + j * 32));
  }

  // ---- theta-phase identity ----
  const int bl = tid >> 6;         // 0..7
  const int ilc = tid & 63;        // 0..63
  const int i  = rg * 64 + ilc;    // my hidden unit
  const int b  = bg * 8 + bl;      // my batch
  float th = 0.f, s_own = 0.f, c_own = 1.f;   // th in REVOLUTIONS

  // ---- init parity-0 state: far-atomic publish (LLC), 32-bit ----
  {
    if ((ilc & 1) == 0)
      stx((uint*)(scT + ((size_t)(0 * 4 + bg) * 16 + bl) * 1024 + i), 0x00000000u);       // sin = 0,0
    else
      stx((uint*)(scT + ((size_t)(0 * 4 + bg) * 16 + bl + 8) * 1024 + (i - 1)), 0x3C003C00u); // cos = 1,1
  }

  unsigned step = 1;
  gbar_pub(flags, step, tid, rg, bg);     // flag 1 guards iteration-0 reads
  float inpv = inp[(size_t)b * NH + i];   // t=0 prefetch drains under the wait

  for (int t = 0; t < T; ++t) {
    const int p = t & 1;

    // ---- per-wave wait on MY 2 producers only, then load my B-slice ----
    wave_wait2(flags, step, lane, bg, w);
    uint4 bf[4];
    ldB4(scT + ((size_t)(p * 4 + bg) * 16 + m) * 1024 + w * 128 + quad * 8, bf);

    // ---- MFMA: 4 independent chains of 4 (one per row-tile) ----
    f32x4 D0 = {0.f, 0.f, 0.f, 0.f}, D1 = {0.f, 0.f, 0.f, 0.f};
    f32x4 D2 = {0.f, 0.f, 0.f, 0.f}, D3 = {0.f, 0.f, 0.f, 0.f};
#pragma unroll
    for (int j = 0; j < 4; ++j) {
      const half8 bh = __builtin_bit_cast(half8, bf[j]);
      D0 = __builtin_amdgcn_mfma_f32_16x16x32_f16(af[0 * 4 + j], bh, D0, 0, 0, 0);
      D1 = __builtin_amdgcn_mfma_f32_16x16x32_f16(af[1 * 4 + j], bh, D1, 0, 0, 0);
      D2 = __builtin_amdgcn_mfma_f32_16x16x32_f16(af[2 * 4 + j], bh, D2, 0, 0, 0);
      D3 = __builtin_amdgcn_mfma_f32_16x16x32_f16(af[3 * 4 + j], bh, D3, 0, 0, 0);
    }

    // lane holds D rows quad*4..+3 (M) of column m (N) -> pd[w][rt][m][quad*4..]
    *(f32x4*)&pd[(((w * 4 + 0) * 16) + m) * PDS + quad * 4] = D0;
    *(f32x4*)&pd[(((w * 4 + 1) * 16) + m) * PDS + quad * 4] = D1;
    *(f32x4*)&pd[(((w * 4 + 2) * 16) + m) * PDS + quad * 4] = D2;
    *(f32x4*)&pd[(((w * 4 + 3) * 16) + m) * PDS + quad * 4] = D3;
    __syncthreads();   // all waves' pd ready AND all 16 flags >= step observed

    // ---- theta update (revolutions, hw trig -- no libm range reduction) ----
    const int rti = ilc >> 4, r16 = ilc & 15;
    float S = 0.f, C = 0.f;
#pragma unroll
    for (int ww = 0; ww < 8; ++ww) {
      S += pd[((ww * 4 + rti) * 16 + bl) * PDS + r16];
      C += pd[((ww * 4 + rti) * 16 + bl + 8) * PDS + r16];
    }
    const float coup = s_own * C - c_own * S;   // sin*ΣWcos - cos*ΣWsin (radians)
    const float thn = th + coup * INV_2PI_F + inpv;
    asm("v_fract_f32 %0, %1" : "=v"(th) : "v"(thn));       // exact mod-1, [0,1)
    asm("v_sin_f32 %0, %1" : "=v"(s_own) : "v"(th));       // sin(th*2pi)
    asm("v_cos_f32 %0, %1" : "=v"(c_own) : "v"(th));       // cos(th*2pi)

    if (t == T - 1) break;

    // ---- publish fp16 state: PACKED 64-bit far atomics (256/block, same bytes) ----
    const uint hs = __builtin_bit_cast(ushort, (_Float16)s_own);
    const uint hc = __builtin_bit_cast(ushort, (_Float16)c_own);
    const uint phs = (uint)__shfl_xor((int)hs, 1, 64);
    const uint phc = (uint)__shfl_xor((int)hc, 1, 64);
    const uint pw = hs | (phs << 16);
    const uint cw = phc | (hc << 16);
    const uint pw2 = (uint)__shfl_xor((int)pw, 2, 64);
    const uint cw2 = (uint)__shfl_xor((int)cw, 2, 64);
    const size_t dbase = (size_t)((p ^ 1) * 4 + bg) * 16;
    if ((ilc & 3) == 0)
      stx64((ull*)(scT + (dbase + bl) * 1024 + i), (ull)pw | ((ull)pw2 << 32));
    else if ((ilc & 3) == 1)
      stx64((ull*)(scT + (dbase + bl + 8) * 1024 + (i - 1)), (ull)cw | ((ull)cw2 << 32));

    gbar_pub(flags, step + 1, tid, rg, bg);               // flag guards t+1 reads
    inpv = inp[((size_t)(t + 1) * BATCH + b) * NH + i];   // drains under next wait
    ++step;
  }

  stF[(size_t)b * NH + i] = th * TWO_PI_F;   // revolutions -> radians

}

// ---- readout ----
__global__ void readout(const float* __restrict__ stF,
                        const float* __restrict__ Wout,   // [10][1024]
                        const float* __restrict__ bout,   // [10]
                        float* __restrict__ out)          // [32][10]
{
  const int bb = blockIdx.x;
  const int lane = threadIdx.x;   // 64 threads
  float st[16];
#pragma unroll
  for (int u = 0; u < 16; ++u) st[u] = stF[(size_t)bb * NH + u * 64 + lane];
  for (int o = 0; o < NOUT; ++o) {
    float acc = 0.f;
#pragma unroll
    for (int u = 0; u < 16; ++u) acc += st[u] * Wout[o * NH + u * 64 + lane];
#pragma unroll
    for (int sh = 1; sh < 64; sh <<= 1) acc += __shfl_xor(acc, sh, 64);
    if (lane == 0) out[bb * NOUT + o] = acc + bout[o];
  }
}

extern "C" void kernel_launch(void* const* d_in, const int* in_sizes, int n_in,
                              void* d_out, int out_size, void* d_ws, size_t ws_size,
                              hipStream_t stream) {
  const float* x     = (const float*)d_in[0];
  const float* Wi_w  = (const float*)d_in[1];
  const float* Wi_b  = (const float*)d_in[2];
  const float* Wh    = (const float*)d_in[3];
  const float* omega = (const float*)d_in[4];
  const float* W_out = (const float*)d_in[5];
  const float* b_out = (const float*)d_in[6];

  char* ws = (char*)d_ws;
  ushort*   w16 = (ushort*)(ws + OFF_W16);
  float*    inp = (float*)(ws + OFF_INP);
  ushort*   scT = (ushort*)(ws + OFF_SCT);
  float*    stF = (float*)(ws + OFF_STF);
  unsigned* flg = (unsigned*)(ws + OFF_FLG);

  (void)hipMemsetAsync(ws + OFF_FLG, 0, 8192, stream);

  prep_w16<<<dim3(NH * NH / 256), dim3(256), 0, stream>>>(Wh, w16);
  prep_inp<<<dim3(T, BATCH), dim3(256), 0, stream>>>(x, Wi_w, Wi_b, omega, inp);

  void* args[] = { (void*)&inp, (void*)&w16, (void*)&scT, (void*)&stF, (void*)&flg };
  hipError_t err = hipLaunchCooperativeKernel((const void*)kuramoto_scan,
                                              dim3(NBLK), dim3(NTHR), args, 0, stream);
  if (err != hipSuccess) {
    // 64 blocks at <=2 blocks/CU are trivially co-resident; normal launch is safe.
    (void)hipGetLastError();
    kuramoto_scan<<<dim3(NBLK), dim3(NTHR), 0, stream>>>(inp, w16, scT, stF, flg);
  }

  readout<<<dim3(BATCH), dim3(64), 0, stream>>>(stF, W_out, b_out, (float*)d_out);
}